// Round 1
// baseline (543.900 us; speedup 1.0000x reference)
//
#include <hip/hip_runtime.h>

#define B_ 8
#define C_ 512
#define T_ 2048
#define E_ 512
#define LN_EPS 1e-5f

typedef __attribute__((ext_vector_type(8))) short bf16x8;
typedef __attribute__((ext_vector_type(4))) float f32x4;

__device__ __forceinline__ unsigned short f2bf(float f) {
  union { float f; unsigned u; } v; v.f = f;
  unsigned u = v.u;
  u += 0x7fff + ((u >> 16) & 1);   // round-to-nearest-even
  return (unsigned short)(u >> 16);
}

// x [B,C,T] fp32 -> residual [B,T,C] fp32 + bf16
__global__ __launch_bounds__(256) void transpose_x(const float* __restrict__ x,
    float* __restrict__ rf, unsigned short* __restrict__ rb) {
  __shared__ float tile[32][33];
  int b = blockIdx.z;
  int t0 = blockIdx.x * 32, c0 = blockIdx.y * 32;
  int tx = threadIdx.x, ty = threadIdx.y;  // 32 x 8
  const float* xb = x + (long)b * C_ * T_;
#pragma unroll
  for (int i = 0; i < 4; i++) {
    int c = c0 + ty + i * 8;
    tile[ty + i * 8][tx] = xb[(long)c * T_ + t0 + tx];
  }
  __syncthreads();
  long ob = (long)b * T_ * C_;
#pragma unroll
  for (int i = 0; i < 4; i++) {
    int t = t0 + ty + i * 8;
    float v = tile[tx][ty + i * 8];
    long idx = ob + (long)t * C_ + c0 + tx;
    rf[idx] = v;
    rb[idx] = f2bf(v);
  }
}

// W [C,E] fp32 -> Wt [E,C] bf16   (square 512x512)
__global__ __launch_bounds__(256) void transpose_w(const float* __restrict__ W,
    unsigned short* __restrict__ Wt) {
  __shared__ float tile[32][33];
  int e0 = blockIdx.x * 32, c0 = blockIdx.y * 32;
  int tx = threadIdx.x, ty = threadIdx.y;
#pragma unroll
  for (int i = 0; i < 4; i++)
    tile[ty + i * 8][tx] = W[(long)(c0 + ty + i * 8) * E_ + e0 + tx];
  __syncthreads();
#pragma unroll
  for (int i = 0; i < 4; i++)
    Wt[(long)(e0 + ty + i * 8) * C_ + c0 + tx] = f2bf(tile[tx][ty + i * 8]);
}

// Unified GEMM: C[m][n] = sum_k A[m][k] * Bt[n][k]  (i.e. C = A @ Bt^T)
// EPI: 0 = bf16 out + bias[n]; 1 = bf16 out + bias[m]; 2 = f32 out + bias[n] + resid;
//      3 = f32 out plain; 4 = bf16 out plain.
// AF32: A is fp32, convert to bf16 while staging.
template<int EPI, bool AF32>
__global__ __launch_bounds__(256) void gemm_bt(
    const void* __restrict__ Ap, const unsigned short* __restrict__ Btp,
    void* __restrict__ Cp, const float* __restrict__ bias,
    const float* __restrict__ resid,
    int M, int N, int K, long sA, long sB, long sC) {
  __shared__ unsigned short As[128][40];
  __shared__ unsigned short Bs[128][40];
  int b = blockIdx.z;
  int tid = threadIdx.x;
  int lane = tid & 63, wave = tid >> 6;
  int wr = (wave >> 1) * 64, wc = (wave & 1) * 64;
  int quad = lane >> 4, l16 = lane & 15;
  long m0 = (long)blockIdx.y * 128, n0 = (long)blockIdx.x * 128;
  const unsigned short* Bt = Btp + (long)b * sB;
  const unsigned short* A16 = (const unsigned short*)Ap + (long)b * sA;
  const float* A32 = (const float*)Ap + (long)b * sA;

  f32x4 acc[4][4] = {};

  for (int k0 = 0; k0 < K; k0 += 32) {
    __syncthreads();
#pragma unroll
    for (int li = 0; li < 2; li++) {
      int idx = tid + li * 256;
      int rr = idx >> 2, cc = (idx & 3) * 8;
      *(bf16x8*)&Bs[rr][cc] = *(const bf16x8*)(Bt + (n0 + rr) * (long)K + k0 + cc);
      if (AF32) {
        const float* s = A32 + (m0 + rr) * (long)K + k0 + cc;
        float4 f0 = *(const float4*)s, f1 = *(const float4*)(s + 4);
        unsigned short tmp[8] = { f2bf(f0.x), f2bf(f0.y), f2bf(f0.z), f2bf(f0.w),
                                  f2bf(f1.x), f2bf(f1.y), f2bf(f1.z), f2bf(f1.w) };
        *(bf16x8*)&As[rr][cc] = *(bf16x8*)tmp;
      } else {
        *(bf16x8*)&As[rr][cc] = *(const bf16x8*)(A16 + (m0 + rr) * (long)K + k0 + cc);
      }
    }
    __syncthreads();
    bf16x8 af[4], bfr[4];
#pragma unroll
    for (int i = 0; i < 4; i++) af[i] = *(const bf16x8*)&As[wr + i * 16 + l16][quad * 8];
#pragma unroll
    for (int j = 0; j < 4; j++) bfr[j] = *(const bf16x8*)&Bs[wc + j * 16 + l16][quad * 8];
#pragma unroll
    for (int i = 0; i < 4; i++)
#pragma unroll
      for (int j = 0; j < 4; j++)
        acc[i][j] = __builtin_amdgcn_mfma_f32_16x16x32_bf16(af[i], bfr[j], acc[i][j], 0, 0, 0);
  }

#pragma unroll
  for (int i = 0; i < 4; i++) {
#pragma unroll
    for (int j = 0; j < 4; j++) {
#pragma unroll
      for (int rr = 0; rr < 4; rr++) {
        long m = m0 + wr + i * 16 + quad * 4 + rr;
        long n = n0 + wc + j * 16 + l16;
        float v = acc[i][j][rr];
        if (EPI == 0)
          ((unsigned short*)Cp)[b * sC + m * N + n] = f2bf(v + bias[n]);
        else if (EPI == 1)
          ((unsigned short*)Cp)[b * sC + m * N + n] = f2bf(v + bias[m]);
        else if (EPI == 2)
          ((float*)Cp)[b * sC + m * N + n] = v + bias[n] + resid[m * (long)N + n];
        else if (EPI == 3)
          ((float*)Cp)[b * sC + m * N + n] = v;
        else
          ((unsigned short*)Cp)[b * sC + m * N + n] = f2bf(v);
      }
    }
  }
}

// in-place softmax over rows of 2048 fp32
__global__ __launch_bounds__(256) void softmax_rows(float* __restrict__ e) {
  long row = blockIdx.x;
  float* p = e + row * (long)T_;
  int tid = threadIdx.x;
  float vals[8];
  float mx = -1e30f;
#pragma unroll
  for (int i = 0; i < 8; i++) { vals[i] = p[tid + i * 256]; mx = fmaxf(mx, vals[i]); }
#pragma unroll
  for (int o = 32; o > 0; o >>= 1) mx = fmaxf(mx, __shfl_xor(mx, o, 64));
  __shared__ float red[4];
  if ((tid & 63) == 0) red[tid >> 6] = mx;
  __syncthreads();
  mx = fmaxf(fmaxf(red[0], red[1]), fmaxf(red[2], red[3]));
  float sum = 0.f;
#pragma unroll
  for (int i = 0; i < 8; i++) { vals[i] = __expf(vals[i] - mx); sum += vals[i]; }
#pragma unroll
  for (int o = 32; o > 0; o >>= 1) sum += __shfl_xor(sum, o, 64);
  __shared__ float red2[4];
  if ((tid & 63) == 0) red2[tid >> 6] = sum;
  __syncthreads();
  sum = red2[0] + red2[1] + red2[2] + red2[3];
  float inv = 1.f / sum;
#pragma unroll
  for (int i = 0; i < 8; i++) p[tid + i * 256] = vals[i] * inv;
}

// LayerNorm over rows of 512 fp32
__global__ __launch_bounds__(256) void layernorm_rows(const float* __restrict__ h,
    const float* __restrict__ gamma, const float* __restrict__ beta,
    float* __restrict__ out) {
  long row = blockIdx.x;
  const float* p = h + row * C_;
  int tid = threadIdx.x;
  float v0 = p[tid], v1 = p[tid + 256];
  float s = v0 + v1, sq = v0 * v0 + v1 * v1;
#pragma unroll
  for (int o = 32; o > 0; o >>= 1) { s += __shfl_xor(s, o, 64); sq += __shfl_xor(sq, o, 64); }
  __shared__ float rs[4], rq[4];
  if ((tid & 63) == 0) { rs[tid >> 6] = s; rq[tid >> 6] = sq; }
  __syncthreads();
  s = rs[0] + rs[1] + rs[2] + rs[3];
  sq = rq[0] + rq[1] + rq[2] + rq[3];
  float mu = s * (1.f / 512.f);
  float var = sq * (1.f / 512.f) - mu * mu;
  float rstd = rsqrtf(var + LN_EPS);
  out[row * C_ + tid] = (v0 - mu) * rstd * gamma[tid] + beta[tid];
  out[row * C_ + tid + 256] = (v1 - mu) * rstd * gamma[tid + 256] + beta[tid + 256];
}

extern "C" void kernel_launch(void* const* d_in, const int* in_sizes, int n_in,
                              void* d_out, int out_size, void* d_ws, size_t ws_size,
                              hipStream_t stream) {
  const float* x  = (const float*)d_in[0];
  const float* Wq = (const float*)d_in[1];
  const float* bq = (const float*)d_in[2];
  const float* Wk = (const float*)d_in[3];
  const float* bk = (const float*)d_in[4];
  const float* Wv = (const float*)d_in[5];
  const float* bv = (const float*)d_in[6];
  const float* Wo = (const float*)d_in[7];
  const float* bo = (const float*)d_in[8];
  const float* gamma = (const float*)d_in[9];
  const float* beta  = (const float*)d_in[10];
  float* out = (float*)d_out;

  char* ws = (char*)d_ws;
  float*          res_f = (float*)ws;                              // 32 MB
  unsigned short* res_b = (unsigned short*)(ws + 33554432);        // 16 MB
  unsigned short* q     = (unsigned short*)(ws + 50331648);        // 16 MB
  unsigned short* k     = (unsigned short*)(ws + 67108864);        // 16 MB
  unsigned short* vt    = (unsigned short*)(ws + 83886080);        // 16 MB  [b][e][s]
  unsigned short* att   = (unsigned short*)(ws + 100663296);       // 16 MB  [b][t][e]
  float*          h     = (float*)(ws + 117440512);                // 32 MB
  unsigned short* WqT   = (unsigned short*)(ws + 150994944);
  unsigned short* WkT   = (unsigned short*)(ws + 150994944 + 524288);
  unsigned short* WvT   = (unsigned short*)(ws + 150994944 + 2 * 524288);
  unsigned short* WoT   = (unsigned short*)(ws + 150994944 + 3 * 524288);

  float* energy = out;                        // attn slot [B,T,T]
  float* outln  = out + (long)B_ * T_ * T_;   // [B,T,C]

  dim3 tb(32, 8);
  transpose_x<<<dim3(T_ / 32, C_ / 32, B_), tb, 0, stream>>>(x, res_f, res_b);
  transpose_w<<<dim3(16, 16), tb, 0, stream>>>(Wq, WqT);
  transpose_w<<<dim3(16, 16), tb, 0, stream>>>(Wk, WkT);
  transpose_w<<<dim3(16, 16), tb, 0, stream>>>(Wv, WvT);
  transpose_w<<<dim3(16, 16), tb, 0, stream>>>(Wo, WoT);

  // q = res @ Wq + bq    [16384 x 512]
  gemm_bt<0, false><<<dim3(4, 128, 1), 256, 0, stream>>>(
      res_b, WqT, q, bq, nullptr, 16384, 512, 512, 0L, 0L, 0L);
  // k = res @ Wk + bk
  gemm_bt<0, false><<<dim3(4, 128, 1), 256, 0, stream>>>(
      res_b, WkT, k, bk, nullptr, 16384, 512, 512, 0L, 0L, 0L);
  // vt[b][e][s] = sum_c WvT[e][c] * res[b][s][c] + bv[e]
  gemm_bt<1, false><<<dim3(16, 4, B_), 256, 0, stream>>>(
      WvT, res_b, vt, bv, nullptr, 512, 2048, 512,
      0L, (long)T_ * C_, (long)E_ * T_);
  // energy[b][t][s] = q[b,t,:] . k[b,s,:]
  gemm_bt<3, false><<<dim3(16, 16, B_), 256, 0, stream>>>(
      q, k, energy, nullptr, nullptr, 2048, 2048, 512,
      (long)T_ * E_, (long)T_ * E_, (long)T_ * T_);
  // softmax rows (in place in d_out)
  softmax_rows<<<dim3(B_ * T_), 256, 0, stream>>>(energy);
  // attended[b][t][e] = sum_s attn[b,t,s] * vt[b,e,s]
  gemm_bt<4, true><<<dim3(4, 16, B_), 256, 0, stream>>>(
      energy, vt, att, nullptr, nullptr, 2048, 512, 2048,
      (long)T_ * T_, (long)E_ * T_, (long)T_ * E_);
  // h = att @ Wo^T' + bo + residual   [16384 x 512] fp32
  gemm_bt<2, false><<<dim3(4, 128, 1), 256, 0, stream>>>(
      att, WoT, h, bo, res_f, 16384, 512, 512, 0L, 0L, 0L);
  // LayerNorm
  layernorm_rows<<<dim3(B_ * T_), 256, 0, stream>>>(h, gamma, beta, outln);
}

// Round 2
// 454.614 us; speedup vs baseline: 1.1964x; 1.1964x over previous
//
#include <hip/hip_runtime.h>

#define B_ 8
#define C_ 512
#define T_ 2048
#define E_ 512
#define LN_EPS 1e-5f

typedef __attribute__((ext_vector_type(8))) short bf16x8;
typedef __attribute__((ext_vector_type(4))) float f32x4;

__device__ __forceinline__ unsigned short f2bf(float f) {
  union { float f; unsigned u; } v; v.f = f;
  unsigned u = v.u;
  u += 0x7fff + ((u >> 16) & 1);   // RNE
  return (unsigned short)(u >> 16);
}
__device__ __forceinline__ float bf2f(unsigned short h) {
  union { unsigned u; float f; } v; v.u = ((unsigned)h) << 16;
  return v.f;
}

// async global->LDS, 16B per lane; LDS dest is wave-uniform base + lane*16
__device__ __forceinline__ void gl2lds16(const unsigned short* g, unsigned short* l) {
  __builtin_amdgcn_global_load_lds(
      (const __attribute__((address_space(1))) unsigned int*)g,
      (__attribute__((address_space(3))) unsigned int*)l, 16, 0, 0);
}

// x [B,C,T] fp32 -> residual [B,T,C] bf16
__global__ __launch_bounds__(256) void transpose_x(const float* __restrict__ x,
    unsigned short* __restrict__ rb) {
  __shared__ float tile[32][33];
  int b = blockIdx.z;
  int t0 = blockIdx.x * 32, c0 = blockIdx.y * 32;
  int tx = threadIdx.x, ty = threadIdx.y;  // 32 x 8
  const float* xb = x + (long)b * C_ * T_;
#pragma unroll
  for (int i = 0; i < 4; i++)
    tile[ty + i * 8][tx] = xb[(long)(c0 + ty + i * 8) * T_ + t0 + tx];
  __syncthreads();
  long ob = (long)b * T_ * C_;
#pragma unroll
  for (int i = 0; i < 4; i++)
    rb[ob + (long)(t0 + ty + i * 8) * C_ + c0 + tx] = f2bf(tile[tx][ty + i * 8]);
}

// W [C,E] fp32 -> Wt [E,C] bf16   (512x512)
__global__ __launch_bounds__(256) void transpose_w(const float* __restrict__ W,
    unsigned short* __restrict__ Wt) {
  __shared__ float tile[32][33];
  int e0 = blockIdx.x * 32, c0 = blockIdx.y * 32;
  int tx = threadIdx.x, ty = threadIdx.y;
#pragma unroll
  for (int i = 0; i < 4; i++)
    tile[ty + i * 8][tx] = W[(long)(c0 + ty + i * 8) * E_ + e0 + tx];
  __syncthreads();
#pragma unroll
  for (int i = 0; i < 4; i++)
    Wt[(long)(e0 + ty + i * 8) * C_ + c0 + tx] = f2bf(tile[tx][ty + i * 8]);
}

__global__ void concat_bias(const float* __restrict__ bq, const float* __restrict__ bk,
                            float* __restrict__ bqk) {
  int i = blockIdx.x * 256 + threadIdx.x;   // 0..1023
  bqk[i] = (i < 512) ? bq[i] : bk[i - 512];
}

// C[m][n] = sum_k A[m][k]*Bt[n][k], bf16 in/out, m97-style staging.
// EPI: 0 = +bias[n]; 1 = +bias[m]; 2 = +bias[n]+bf16 resid[m*ldc+n]; 4 = plain.
template<int EPI>
__global__ __launch_bounds__(256) void gemm_bt(
    const unsigned short* __restrict__ Ap, const unsigned short* __restrict__ Btp,
    unsigned short* __restrict__ Cp, const float* __restrict__ bias,
    const unsigned short* __restrict__ resid,
    int K, int lda, int ldb, int ldc, long sA, long sB, long sC) {
  __shared__ unsigned short As[128 * 32];
  __shared__ unsigned short Bs[128 * 32];
  const int b = blockIdx.z;
  const int tid = threadIdx.x;
  const int lane = tid & 63, wave = tid >> 6;
  const int wr = (wave >> 1) * 64, wc = (wave & 1) * 64;
  const int quad = lane >> 4, l16 = lane & 15;
  const long m0 = (long)blockIdx.y * 128, n0 = (long)blockIdx.x * 128;
  const unsigned short* A  = Ap  + (long)b * sA;
  const unsigned short* Bt = Btp + (long)b * sB;

  // staging geometry: wave w owns tile rows [32w, 32w+32); one inst = 16 rows (1KB)
  const int srow = lane >> 2;        // 0..15
  const int soff = (lane & 3) * 8;   // shorts within row (16B chunks)
  const int ra = wave * 32;
  const unsigned short* ga = A  + (m0 + ra + srow) * (long)lda + soff;
  const unsigned short* gb = Bt + (n0 + ra + srow) * (long)ldb + soff;
  unsigned short* la0 = &As[ra * 32];
  unsigned short* la1 = &As[(ra + 16) * 32];
  unsigned short* lb0 = &Bs[ra * 32];
  unsigned short* lb1 = &Bs[(ra + 16) * 32];

  f32x4 acc[4][4] = {};

  for (int k0 = 0; k0 < K; k0 += 32) {
    __syncthreads();
    gl2lds16(ga + k0, la0);
    gl2lds16(ga + 16 * (long)lda + k0, la1);
    gl2lds16(gb + k0, lb0);
    gl2lds16(gb + 16 * (long)ldb + k0, lb1);
    __syncthreads();
    bf16x8 af[4], bfr[4];
#pragma unroll
    for (int i = 0; i < 4; i++)
      af[i] = *(const bf16x8*)&As[(wr + i * 16 + l16) * 32 + quad * 8];
#pragma unroll
    for (int j = 0; j < 4; j++)
      bfr[j] = *(const bf16x8*)&Bs[(wc + j * 16 + l16) * 32 + quad * 8];
#pragma unroll
    for (int i = 0; i < 4; i++)
#pragma unroll
      for (int j = 0; j < 4; j++)
        acc[i][j] = __builtin_amdgcn_mfma_f32_16x16x32_bf16(af[i], bfr[j], acc[i][j], 0, 0, 0);
  }

  const long cb = (long)b * sC;
#pragma unroll
  for (int i = 0; i < 4; i++) {
#pragma unroll
    for (int rr = 0; rr < 4; rr++) {
      const long m = m0 + wr + i * 16 + quad * 4 + rr;
#pragma unroll
      for (int j = 0; j < 4; j++) {
        const long n = n0 + wc + j * 16 + l16;
        float v = acc[i][j][rr];
        if (EPI == 0) v += bias[n];
        else if (EPI == 1) v += bias[m];
        else if (EPI == 2) v += bias[n] + bf2f(resid[m * (long)ldc + n]);
        Cp[cb + m * (long)ldc + n] = f2bf(v);
      }
    }
  }
}

// softmax over rows of 2048: read bf16 energy, write f32 attn (d_out) + bf16 attn in-place
__global__ __launch_bounds__(256) void softmax_rows(unsigned short* __restrict__ eb,
                                                    float* __restrict__ attn) {
  long row = blockIdx.x;
  unsigned short* p = eb + row * (long)T_;
  float* o = attn + row * (long)T_;
  int tid = threadIdx.x;
  bf16x8 raw = *(const bf16x8*)(p + tid * 8);
  float vals[8];
  float mx = -1e30f;
#pragma unroll
  for (int i = 0; i < 8; i++) {
    vals[i] = bf2f((unsigned short)raw[i]);
    mx = fmaxf(mx, vals[i]);
  }
#pragma unroll
  for (int o2 = 32; o2 > 0; o2 >>= 1) mx = fmaxf(mx, __shfl_xor(mx, o2, 64));
  __shared__ float red[4];
  if ((tid & 63) == 0) red[tid >> 6] = mx;
  __syncthreads();
  mx = fmaxf(fmaxf(red[0], red[1]), fmaxf(red[2], red[3]));
  float sum = 0.f;
#pragma unroll
  for (int i = 0; i < 8; i++) { vals[i] = __expf(vals[i] - mx); sum += vals[i]; }
#pragma unroll
  for (int o2 = 32; o2 > 0; o2 >>= 1) sum += __shfl_xor(sum, o2, 64);
  __shared__ float red2[4];
  if ((tid & 63) == 0) red2[tid >> 6] = sum;
  __syncthreads();
  sum = red2[0] + red2[1] + red2[2] + red2[3];
  float inv = 1.f / sum;
  unsigned short ob[8];
  float r0[4], r1[4];
#pragma unroll
  for (int i = 0; i < 8; i++) {
    float r = vals[i] * inv;
    if (i < 4) r0[i] = r; else r1[i - 4] = r;
    ob[i] = f2bf(r);
  }
  *(float4*)(o + tid * 8)     = *(float4*)r0;
  *(float4*)(o + tid * 8 + 4) = *(float4*)r1;
  *(bf16x8*)(p + tid * 8) = *(bf16x8*)ob;
}

// LayerNorm over rows of 512, bf16 input, f32 output
__global__ __launch_bounds__(256) void layernorm_rows(const unsigned short* __restrict__ hb,
    const float* __restrict__ gamma, const float* __restrict__ beta,
    float* __restrict__ out) {
  long row = blockIdx.x;
  const unsigned short* p = hb + row * C_;
  int tid = threadIdx.x;
  unsigned pr = *(const unsigned*)(p + 2 * tid);
  float v0 = bf2f((unsigned short)(pr & 0xffff));
  float v1 = bf2f((unsigned short)(pr >> 16));
  float s = v0 + v1, sq = v0 * v0 + v1 * v1;
#pragma unroll
  for (int o = 32; o > 0; o >>= 1) { s += __shfl_xor(s, o, 64); sq += __shfl_xor(sq, o, 64); }
  __shared__ float rs[4], rq[4];
  if ((tid & 63) == 0) { rs[tid >> 6] = s; rq[tid >> 6] = sq; }
  __syncthreads();
  s = rs[0] + rs[1] + rs[2] + rs[3];
  sq = rq[0] + rq[1] + rq[2] + rq[3];
  float mu = s * (1.f / 512.f);
  float var = sq * (1.f / 512.f) - mu * mu;
  float rstd = rsqrtf(var + LN_EPS);
  out[row * C_ + 2 * tid]     = (v0 - mu) * rstd * gamma[2 * tid] + beta[2 * tid];
  out[row * C_ + 2 * tid + 1] = (v1 - mu) * rstd * gamma[2 * tid + 1] + beta[2 * tid + 1];
}

extern "C" void kernel_launch(void* const* d_in, const int* in_sizes, int n_in,
                              void* d_out, int out_size, void* d_ws, size_t ws_size,
                              hipStream_t stream) {
  const float* x  = (const float*)d_in[0];
  const float* Wq = (const float*)d_in[1];
  const float* bq = (const float*)d_in[2];
  const float* Wk = (const float*)d_in[3];
  const float* bk = (const float*)d_in[4];
  const float* Wv = (const float*)d_in[5];
  const float* bv = (const float*)d_in[6];
  const float* Wo = (const float*)d_in[7];
  const float* bo = (const float*)d_in[8];
  const float* gamma = (const float*)d_in[9];
  const float* beta  = (const float*)d_in[10];
  float* out = (float*)d_out;

  char* ws = (char*)d_ws;
  unsigned short* res_b = (unsigned short*)ws;                          // 16 MB [16384][512]
  unsigned short* qk    = (unsigned short*)(ws + (16ul << 20));         // 32 MB [16384][1024]
  unsigned short* att   = (unsigned short*)(ws + (16ul << 20));         // overlay (q dead)
  unsigned short* hb    = (unsigned short*)(ws + (32ul << 20));         // overlay (k dead)
  unsigned short* vt    = (unsigned short*)(ws + (48ul << 20));         // 16 MB [b][512][2048]
  unsigned short* eb    = (unsigned short*)(ws + (64ul << 20));         // 64 MB [b][2048][2048]
  unsigned short* WqkT  = (unsigned short*)(ws + (128ul << 20));        // 2 MB [1024][512]
  unsigned short* WvT   = (unsigned short*)(ws + (130ul << 20));        // 512 KB
  unsigned short* WoT   = (unsigned short*)(ws + (130ul << 20) + 524288);
  float*          bqk   = (float*)(ws + (131ul << 20));                 // 4 KB

  float* attn_f = out;                        // [B,T,T]
  float* outln  = out + (long)B_ * T_ * T_;   // [B,T,C]

  dim3 tb(32, 8);
  transpose_x<<<dim3(T_ / 32, C_ / 32, B_), tb, 0, stream>>>(x, res_b);
  transpose_w<<<dim3(16, 16), tb, 0, stream>>>(Wq, WqkT);
  transpose_w<<<dim3(16, 16), tb, 0, stream>>>(Wk, WqkT + 512 * 512);
  transpose_w<<<dim3(16, 16), tb, 0, stream>>>(Wv, WvT);
  transpose_w<<<dim3(16, 16), tb, 0, stream>>>(Wo, WoT);
  concat_bias<<<dim3(4), 256, 0, stream>>>(bq, bk, bqk);

  // qk = res @ [Wq|Wk] + [bq|bk]   [16384 x 1024], K=512
  gemm_bt<0><<<dim3(8, 128, 1), 256, 0, stream>>>(
      res_b, WqkT, qk, bqk, nullptr, 512, 512, 512, 1024, 0L, 0L, 0L);
  // vt[b][e][s] = WvT[e,:] . res[b][s,:] + bv[e]   M=512, N=2048, K=512
  gemm_bt<1><<<dim3(16, 4, B_), 256, 0, stream>>>(
      WvT, res_b, vt, bv, nullptr, 512, 512, 512, 2048,
      0L, (long)T_ * C_, 512L * 2048);
  // energy bf16: q[b,t,:] . k[b,s,:]   M=N=2048, K=512
  gemm_bt<4><<<dim3(16, 16, B_), 256, 0, stream>>>(
      qk, qk + 512, eb, nullptr, nullptr, 512, 1024, 1024, 2048,
      (long)T_ * 1024, (long)T_ * 1024, (long)T_ * T_);
  // softmax: f32 attn to d_out, bf16 attn in-place
  softmax_rows<<<dim3(B_ * T_), 256, 0, stream>>>(eb, attn_f);
  // attended[b][t][e] = attn[b,t,:] . vt[b,e,:]   M=2048, N=512, K=2048
  gemm_bt<4><<<dim3(4, 16, B_), 256, 0, stream>>>(
      eb, vt, att, nullptr, nullptr, 2048, 2048, 2048, 512,
      (long)T_ * T_, 512L * 2048, (long)T_ * 512);
  // h = att @ WoT^T + bo + resid (bf16)   [16384 x 512], K=512
  gemm_bt<2><<<dim3(4, 128, 1), 256, 0, stream>>>(
      att, WoT, hb, bo, res_b, 512, 512, 512, 512, 0L, 0L, 0L);
  // LayerNorm
  layernorm_rows<<<dim3(B_ * T_), 256, 0, stream>>>(hb, gamma, beta, outln);
}

// Round 3
// 423.671 us; speedup vs baseline: 1.2838x; 1.0730x over previous
//
#include <hip/hip_runtime.h>

#define B_ 8
#define C_ 512
#define T_ 2048
#define E_ 512
#define LN_EPS 1e-5f

typedef __attribute__((ext_vector_type(8))) short bf16x8;
typedef __attribute__((ext_vector_type(4))) float f32x4;

__device__ __forceinline__ unsigned short f2bf(float f) {
  union { float f; unsigned u; } v; v.f = f;
  unsigned u = v.u;
  u += 0x7fff + ((u >> 16) & 1);   // RNE
  return (unsigned short)(u >> 16);
}
__device__ __forceinline__ float bf2f(unsigned short h) {
  union { unsigned u; float f; } v; v.u = ((unsigned)h) << 16;
  return v.f;
}

// async global->LDS, 16B/lane; LDS dest = wave-uniform base + lane*16
__device__ __forceinline__ void gl2lds16(const unsigned short* g, unsigned short* l) {
  __builtin_amdgcn_global_load_lds(
      (const __attribute__((address_space(1))) unsigned int*)g,
      (__attribute__((address_space(3))) unsigned int*)l, 16, 0, 0);
}

// x [B,C,T] fp32 -> residual [B,T,C] bf16
__global__ __launch_bounds__(256) void transpose_x(const float* __restrict__ x,
    unsigned short* __restrict__ rb) {
  __shared__ float tile[32][33];
  int b = blockIdx.z;
  int t0 = blockIdx.x * 32, c0 = blockIdx.y * 32;
  int tx = threadIdx.x, ty = threadIdx.y;  // 32 x 8
  const float* xb = x + (long)b * C_ * T_;
#pragma unroll
  for (int i = 0; i < 4; i++)
    tile[ty + i * 8][tx] = xb[(long)(c0 + ty + i * 8) * T_ + t0 + tx];
  __syncthreads();
  long ob = (long)b * T_ * C_;
#pragma unroll
  for (int i = 0; i < 4; i++)
    rb[ob + (long)(t0 + ty + i * 8) * C_ + c0 + tx] = f2bf(tile[tx][ty + i * 8]);
}

// W [C,E] fp32 -> Wt [E,C] bf16   (512x512)
__global__ __launch_bounds__(256) void transpose_w(const float* __restrict__ W,
    unsigned short* __restrict__ Wt) {
  __shared__ float tile[32][33];
  int e0 = blockIdx.x * 32, c0 = blockIdx.y * 32;
  int tx = threadIdx.x, ty = threadIdx.y;
#pragma unroll
  for (int i = 0; i < 4; i++)
    tile[ty + i * 8][tx] = W[(long)(c0 + ty + i * 8) * E_ + e0 + tx];
  __syncthreads();
#pragma unroll
  for (int i = 0; i < 4; i++)
    Wt[(long)(e0 + ty + i * 8) * C_ + c0 + tx] = f2bf(tile[tx][ty + i * 8]);
}

__global__ void concat_bias(const float* __restrict__ bq, const float* __restrict__ bk,
                            float* __restrict__ bqk) {
  int i = blockIdx.x * 256 + threadIdx.x;   // 0..1023
  bqk[i] = (i < 512) ? bq[i] : bk[i - 512];
}

// C[m][n] = sum_k A[m][k]*Bt[n][k], bf16 in/out. BK=64, XOR-swizzled LDS.
// BM = 128 or 64 (BN fixed 128). EPI: 0=+bias[n]; 1=+bias[m]; 2=+bias[n]+resid; 4=plain.
template<int EPI, int BM>
__global__ __launch_bounds__(256) void gemm_bt(
    const unsigned short* __restrict__ Ap, const unsigned short* __restrict__ Btp,
    unsigned short* __restrict__ Cp, const float* __restrict__ bias,
    const unsigned short* __restrict__ resid,
    int K, int lda, int ldb, int ldc, long sA, long sB, long sC) {
  __shared__ unsigned short As[BM * 64];
  __shared__ unsigned short Bs[128 * 64];
  constexpr int WI = BM / 32;                 // 16-row tiles per wave (M)
  const int b = blockIdx.z;
  const int tid = threadIdx.x;
  const int lane = tid & 63, wave = tid >> 6;
  const int wr = (wave >> 1) * (BM / 2);
  const int wc = (wave & 1) * 64;
  const int quad = lane >> 4, l16 = lane & 15;
  const long m0 = (long)blockIdx.y * BM, n0 = (long)blockIdx.x * 128;

  // staging: one inst = 8 rows x 64 shorts (1KB). Global column XOR-permuted
  // per row so LDS chunk p of row r holds global chunk p^(r&7).
  const int srow = lane >> 3;                   // 0..7
  const int gcol = ((lane & 7) ^ srow) * 8;     // swizzled 16B chunk
  const unsigned short* ga = Ap + (long)b * sA + (m0 + srow) * (long)lda + gcol;
  const unsigned short* gb = Btp + (long)b * sB + (n0 + srow) * (long)ldb + gcol;

  f32x4 acc[WI][4] = {};

  for (int k0 = 0; k0 < K; k0 += 64) {
    __syncthreads();
#pragma unroll
    for (int s = 0; s < WI; s++)
      gl2lds16(ga + (s * 32 + wave * 8) * (long)lda + k0, &As[(s * 32 + wave * 8) * 64]);
#pragma unroll
    for (int s = 0; s < 4; s++)
      gl2lds16(gb + (s * 32 + wave * 8) * (long)ldb + k0, &Bs[(s * 32 + wave * 8) * 64]);
    __syncthreads();
#pragma unroll
    for (int ks = 0; ks < 2; ks++) {
      const int cs = ((ks * 4 + quad) ^ (l16 & 7)) * 8;   // un-swizzle
      bf16x8 af[WI], bfr[4];
#pragma unroll
      for (int i = 0; i < WI; i++)
        af[i] = *(const bf16x8*)&As[(wr + i * 16 + l16) * 64 + cs];
#pragma unroll
      for (int j = 0; j < 4; j++)
        bfr[j] = *(const bf16x8*)&Bs[(wc + j * 16 + l16) * 64 + cs];
#pragma unroll
      for (int i = 0; i < WI; i++)
#pragma unroll
        for (int j = 0; j < 4; j++)
          acc[i][j] = __builtin_amdgcn_mfma_f32_16x16x32_bf16(af[i], bfr[j], acc[i][j], 0, 0, 0);
    }
  }

  const long cb = (long)b * sC;
#pragma unroll
  for (int i = 0; i < WI; i++) {
#pragma unroll
    for (int rr = 0; rr < 4; rr++) {
      const long m = m0 + wr + i * 16 + quad * 4 + rr;
#pragma unroll
      for (int j = 0; j < 4; j++) {
        const long n = n0 + wc + j * 16 + l16;
        float v = acc[i][j][rr];
        if (EPI == 0) v += bias[n];
        else if (EPI == 1) v += bias[m];
        else if (EPI == 2) v += bias[n] + bf2f(resid[m * (long)ldc + n]);
        Cp[cb + m * (long)ldc + n] = f2bf(v);
      }
    }
  }
}

// softmax over rows of 2048: read bf16 energy, write f32 attn (d_out) + bf16 in-place
__global__ __launch_bounds__(256) void softmax_rows(unsigned short* __restrict__ eb,
                                                    float* __restrict__ attn) {
  long row = blockIdx.x;
  unsigned short* p = eb + row * (long)T_;
  float* o = attn + row * (long)T_;
  int tid = threadIdx.x;
  bf16x8 raw = *(const bf16x8*)(p + tid * 8);
  float vals[8];
  float mx = -1e30f;
#pragma unroll
  for (int i = 0; i < 8; i++) {
    vals[i] = bf2f((unsigned short)raw[i]);
    mx = fmaxf(mx, vals[i]);
  }
#pragma unroll
  for (int o2 = 32; o2 > 0; o2 >>= 1) mx = fmaxf(mx, __shfl_xor(mx, o2, 64));
  __shared__ float red[4];
  if ((tid & 63) == 0) red[tid >> 6] = mx;
  __syncthreads();
  mx = fmaxf(fmaxf(red[0], red[1]), fmaxf(red[2], red[3]));
  float sum = 0.f;
#pragma unroll
  for (int i = 0; i < 8; i++) { vals[i] = __expf(vals[i] - mx); sum += vals[i]; }
#pragma unroll
  for (int o2 = 32; o2 > 0; o2 >>= 1) sum += __shfl_xor(sum, o2, 64);
  __shared__ float red2[4];
  if ((tid & 63) == 0) red2[tid >> 6] = sum;
  __syncthreads();
  sum = red2[0] + red2[1] + red2[2] + red2[3];
  float inv = 1.f / sum;
  unsigned short ob[8];
  float r0[4], r1[4];
#pragma unroll
  for (int i = 0; i < 8; i++) {
    float r = vals[i] * inv;
    if (i < 4) r0[i] = r; else r1[i - 4] = r;
    ob[i] = f2bf(r);
  }
  *(float4*)(o + tid * 8)     = *(float4*)r0;
  *(float4*)(o + tid * 8 + 4) = *(float4*)r1;
  *(bf16x8*)(p + tid * 8) = *(bf16x8*)ob;
}

// LayerNorm over rows of 512, bf16 input, f32 output
__global__ __launch_bounds__(256) void layernorm_rows(const unsigned short* __restrict__ hb,
    const float* __restrict__ gamma, const float* __restrict__ beta,
    float* __restrict__ out) {
  long row = blockIdx.x;
  const unsigned short* p = hb + row * C_;
  int tid = threadIdx.x;
  unsigned pr = *(const unsigned*)(p + 2 * tid);
  float v0 = bf2f((unsigned short)(pr & 0xffff));
  float v1 = bf2f((unsigned short)(pr >> 16));
  float s = v0 + v1, sq = v0 * v0 + v1 * v1;
#pragma unroll
  for (int o = 32; o > 0; o >>= 1) { s += __shfl_xor(s, o, 64); sq += __shfl_xor(sq, o, 64); }
  __shared__ float rs[4], rq[4];
  if ((tid & 63) == 0) { rs[tid >> 6] = s; rq[tid >> 6] = sq; }
  __syncthreads();
  s = rs[0] + rs[1] + rs[2] + rs[3];
  sq = rq[0] + rq[1] + rq[2] + rq[3];
  float mu = s * (1.f / 512.f);
  float var = sq * (1.f / 512.f) - mu * mu;
  float rstd = rsqrtf(var + LN_EPS);
  out[row * C_ + 2 * tid]     = (v0 - mu) * rstd * gamma[2 * tid] + beta[2 * tid];
  out[row * C_ + 2 * tid + 1] = (v1 - mu) * rstd * gamma[2 * tid + 1] + beta[2 * tid + 1];
}

extern "C" void kernel_launch(void* const* d_in, const int* in_sizes, int n_in,
                              void* d_out, int out_size, void* d_ws, size_t ws_size,
                              hipStream_t stream) {
  const float* x  = (const float*)d_in[0];
  const float* Wq = (const float*)d_in[1];
  const float* bq = (const float*)d_in[2];
  const float* Wk = (const float*)d_in[3];
  const float* bk = (const float*)d_in[4];
  const float* Wv = (const float*)d_in[5];
  const float* bv = (const float*)d_in[6];
  const float* Wo = (const float*)d_in[7];
  const float* bo = (const float*)d_in[8];
  const float* gamma = (const float*)d_in[9];
  const float* beta  = (const float*)d_in[10];
  float* out = (float*)d_out;

  char* ws = (char*)d_ws;
  unsigned short* res_b = (unsigned short*)ws;                          // 16 MB [16384][512]
  unsigned short* qk    = (unsigned short*)(ws + (16ul << 20));         // 32 MB [16384][1024]
  unsigned short* att   = (unsigned short*)(ws + (16ul << 20));         // overlay (q dead)
  unsigned short* hb    = (unsigned short*)(ws + (32ul << 20));         // overlay (k dead)
  unsigned short* vt    = (unsigned short*)(ws + (48ul << 20));         // 16 MB [b][512][2048]
  unsigned short* eb    = (unsigned short*)(ws + (64ul << 20));         // 64 MB [b][2048][2048]
  unsigned short* WqkT  = (unsigned short*)(ws + (128ul << 20));        // 2 MB [1024][512]
  unsigned short* WvT   = (unsigned short*)(ws + (130ul << 20));        // 512 KB
  unsigned short* WoT   = (unsigned short*)(ws + (130ul << 20) + 524288);
  float*          bqk   = (float*)(ws + (131ul << 20));                 // 4 KB

  float* attn_f = out;                        // [B,T,T]
  float* outln  = out + (long)B_ * T_ * T_;   // [B,T,C]

  dim3 tb(32, 8);
  transpose_x<<<dim3(T_ / 32, C_ / 32, B_), tb, 0, stream>>>(x, res_b);
  transpose_w<<<dim3(16, 16), tb, 0, stream>>>(Wq, WqkT);
  transpose_w<<<dim3(16, 16), tb, 0, stream>>>(Wk, WqkT + 512 * 512);
  transpose_w<<<dim3(16, 16), tb, 0, stream>>>(Wv, WvT);
  transpose_w<<<dim3(16, 16), tb, 0, stream>>>(Wo, WoT);
  concat_bias<<<dim3(4), 256, 0, stream>>>(bq, bk, bqk);

  // qk = res @ [Wq|Wk] + [bq|bk]   [16384 x 1024], K=512
  gemm_bt<0, 128><<<dim3(8, 128, 1), 256, 0, stream>>>(
      res_b, WqkT, qk, bqk, nullptr, 512, 512, 512, 1024, 0L, 0L, 0L);
  // vt[b][e][s] = WvT[e,:] . res[b][s,:] + bv[e]   M=512, N=2048, K=512
  gemm_bt<1, 64><<<dim3(16, 8, B_), 256, 0, stream>>>(
      WvT, res_b, vt, bv, nullptr, 512, 512, 512, 2048,
      0L, (long)T_ * C_, 512L * 2048);
  // energy bf16: q[b,t,:] . k[b,s,:]   M=N=2048, K=512
  gemm_bt<4, 128><<<dim3(16, 16, B_), 256, 0, stream>>>(
      qk, qk + 512, eb, nullptr, nullptr, 512, 1024, 1024, 2048,
      (long)T_ * 1024, (long)T_ * 1024, (long)T_ * T_);
  // softmax: f32 attn to d_out, bf16 attn in-place
  softmax_rows<<<dim3(B_ * T_), 256, 0, stream>>>(eb, attn_f);
  // attended[b][t][e] = attn[b,t,:] . vt[b,e,:]   M=2048, N=512, K=2048
  gemm_bt<4, 64><<<dim3(4, 32, B_), 256, 0, stream>>>(
      eb, vt, att, nullptr, nullptr, 2048, 2048, 2048, 512,
      (long)T_ * T_, 512L * 2048, (long)T_ * 512);
  // h = att @ WoT^T + bo + resid (bf16)   [16384 x 512], K=512
  gemm_bt<2, 64><<<dim3(4, 256, 1), 256, 0, stream>>>(
      att, WoT, hb, bo, res_b, 512, 512, 512, 512, 0L, 0L, 0L);
  // LayerNorm
  layernorm_rows<<<dim3(B_ * T_), 256, 0, stream>>>(hb, gamma, beta, outln);
}